// Round 5
// baseline (271.668 us; speedup 1.0000x reference)
//
#include <hip/hip_runtime.h>
#include <math.h>

#define BB 8
#define TT 4096
#define TP1 4097
#define HH 1024
#define NHD 16

__device__ __forceinline__ float dot4(const float4& a, const float4& b) {
  return a.x*b.x + a.y*b.y + a.z*b.z + a.w*b.w;
}

// ---------------- K1: qbuf[b][j] = 0.125*(cell[b,:]·Wq[j,:] + bq[j]) ----------------
__global__ __launch_bounds__(256) void k_q(const float* __restrict__ cell,
                                           const float* __restrict__ Wq,
                                           const float* __restrict__ bq,
                                           float* __restrict__ qbuf) {
  __shared__ float cs[BB * HH];  // 32 KB
  int tid = threadIdx.x;
  #pragma unroll
  for (int m = 0; m < 8; m++) {
    int idx4 = tid + (m << 8);
    ((float4*)cs)[idx4] = ((const float4*)cell)[idx4];
  }
  __syncthreads();
  int jj = tid >> 6, lane = tid & 63;
  int j = blockIdx.x * 4 + jj;
  float acc[BB];
  #pragma unroll
  for (int b = 0; b < BB; b++) acc[b] = 0.f;
  #pragma unroll
  for (int k = 0; k < 4; k++) {
    int i = (k << 8) + (lane << 2);
    float4 w = *(const float4*)&Wq[(size_t)j * HH + i];
    #pragma unroll
    for (int b = 0; b < BB; b++) acc[b] += dot4(w, *(const float4*)&cs[b * HH + i]);
  }
  #pragma unroll
  for (int b = 0; b < BB; b++) {
    acc[b] += __shfl_xor(acc[b], 1);  acc[b] += __shfl_xor(acc[b], 2);
    acc[b] += __shfl_xor(acc[b], 4);  acc[b] += __shfl_xor(acc[b], 8);
    acc[b] += __shfl_xor(acc[b], 16); acc[b] += __shfl_xor(acc[b], 32);
  }
  if (lane == 0) {
    float bqv = bq[j];
    #pragma unroll
    for (int b = 0; b < BB; b++) qbuf[b * HH + j] = 0.125f * (acc[b] + bqv);
  }
}

// ---------------- K2: qWkT[b][i][h] = sum_d qbuf[b][h*64+d]*Wk[h*64+d][i]; qbk[b][h] ----------------
__global__ __launch_bounds__(256) void k_qwk(const float* __restrict__ qbuf,
                                             const float* __restrict__ Wk,
                                             const float* __restrict__ bk,
                                             float* __restrict__ qWkT,
                                             float* __restrict__ qbk) {
  __shared__ float q_s[BB * 64];
  __shared__ float red[4 * 64 * 9];  // padded +1
  int tid = threadIdx.x;
  int h = blockIdx.x >> 4, ic = blockIdx.x & 15;
  if (tid < 128) {
    int b = tid >> 4, dq = tid & 15;
    ((float4*)q_s)[tid] = ((const float4*)qbuf)[(b << 8) + (h << 4) + dq];
  }
  __syncthreads();
  int dg = tid >> 6, lane = tid & 63;
  int i = (ic << 6) + lane;
  float acc[BB];
  #pragma unroll
  for (int b = 0; b < BB; b++) acc[b] = 0.f;
  #pragma unroll
  for (int dd = 0; dd < 16; dd++) {
    int d = (dg << 4) + dd;
    float wk = Wk[(size_t)((h << 6) + d) * HH + i];
    #pragma unroll
    for (int b = 0; b < BB; b++) acc[b] += q_s[(b << 6) + d] * wk;
  }
  #pragma unroll
  for (int b = 0; b < BB; b++) red[((dg << 6) + lane) * 9 + b] = acc[b];
  __syncthreads();
  #pragma unroll
  for (int r = 0; r < 2; r++) {
    int o = tid + (r << 8);           // 512 outputs = 64 i x 8 b
    int il = o >> 3, b = o & 7;
    float s = 0.f;
    #pragma unroll
    for (int g = 0; g < 4; g++) s += red[((g << 6) + il) * 9 + b];
    qWkT[((size_t)(b << 10) + (ic << 6) + il) * NHD + h] = s;
  }
  if (ic == 0 && tid < 8) {
    float s = 0.f;
    for (int d = 0; d < 64; d++) s += q_s[(tid << 6) + d] * bk[(h << 6) + d];
    qbk[tid * NHD + h] = s;
  }
}

// ---------------- K3 (FUSED v5): 64-i chunks, dbuf, 4 blocks/CU for TLP overlap ----------------
// grid 512 = b(8) x g(64); block 512 thr (8 waves); 64 rows/block.
// 16 chunks of 64 i; KV double-buffered [2][64][64] = 32 KB linear LDS via
// global_load_lds width=16 (source quad XOR-swizzled by row&7, reads same XOR).
// LDS total: KV 8192 + E[64][20] 1280 = 9472 floats = 37.9 KB -> 4 blocks/CU
// (32 waves/CU): independent blocks phase-shift -> HBM/VALU/LDS pipes overlap.
// One barrier per chunk (publishes async loads + protects swap); STAGE(c+1)
// issued before compute(c).
// Scores: lane = row; wave w owns i-quads {2w, 2w+1}; q via wave-uniform float4
// loads (scalarize to s_load). acc[16]/lane persists across chunks.
// Red: two-stage overlay red2[4][64][17] in the (dead) KV region.
// PV: re-stage chunks (hid L3-resident); waves 0-3: hq=w; lane = (grp=lane>>4,
// iq=lane&15); rows split 4 ways, combined via shfl_xor(16,32); lanes 0-15 write.
__global__ __launch_bounds__(512) void k_sctx(const float* __restrict__ hid,
                                              const float* __restrict__ qWkT,
                                              const float* __restrict__ qbk,
                                              const int* __restrict__ mask,
                                              float* __restrict__ ctxp,
                                              float* __restrict__ Spart) {
  __shared__ float S[9472];   // KV[2][64][64] = 8192; E at 8192 ([64][20]); red2 overlay [4][64][17]
  int tid = threadIdx.x;
  int b = blockIdx.x >> 6, g = blockIdx.x & 63;
  int t0 = g << 6;
  int w = __builtin_amdgcn_readfirstlane(tid >> 6);
  int lane = tid & 63;
  const float* src = hid + ((size_t)b * TP1 + t0) * HH;
  int rsub = lane >> 4, q15 = lane & 15;
  #define E_OFF 8192

  // async stage of chunk cc (64 i) into buffer buf; wave w stages rows w*8..w*8+7
  #define STAGE(cc, buf)                                                            \
    {                                                                               \
      _Pragma("unroll")                                                             \
      for (int j = 0; j < 2; j++) {                                                 \
        int row0 = (w << 3) + (j << 2);                                             \
        int row = row0 + rsub;                                                      \
        const float* gp = src + (size_t)row * HH + ((cc) << 6) +                    \
                          ((q15 ^ (row & 7)) << 2);                                 \
        float* dp = &S[((buf) << 12) + (row0 << 6)];                                \
        __builtin_amdgcn_global_load_lds(                                           \
            (const __attribute__((address_space(1))) unsigned int*)gp,              \
            (__attribute__((address_space(3))) unsigned int*)dp, 16, 0, 0);         \
      }                                                                             \
    }

  // ---------------- scores pass ----------------
  STAGE(0, 0);
  __syncthreads();

  float acc[16];
  #pragma unroll
  for (int h = 0; h < 16; h++) acc[h] = 0.f;
  const float* qb = qWkT + ((size_t)b << 14);

  for (int c = 0; c < 16; c++) {
    if (c < 15) STAGE(c + 1, (c + 1) & 1);
    const float* sb = &S[(c & 1) << 12];
    #pragma unroll
    for (int s = 0; s < 2; s++) {
      int q = (w << 1) + s;
      float4 kvq = *(const float4*)&sb[(lane << 6) + ((q ^ (lane & 7)) << 2)];
      const float* qp = qb + (((size_t)(c << 6) + (q << 2)) << 4);
      #pragma unroll
      for (int ii = 0; ii < 4; ii++) {
        float kvv = (ii == 0) ? kvq.x : (ii == 1) ? kvq.y : (ii == 2) ? kvq.z : kvq.w;
        const float* qi = qp + (ii << 4);
        float4 q0 = *(const float4*)(qi);
        float4 q1 = *(const float4*)(qi + 4);
        float4 q2 = *(const float4*)(qi + 8);
        float4 q3 = *(const float4*)(qi + 12);
        acc[0]  += kvv * q0.x;  acc[1]  += kvv * q0.y;
        acc[2]  += kvv * q0.z;  acc[3]  += kvv * q0.w;
        acc[4]  += kvv * q1.x;  acc[5]  += kvv * q1.y;
        acc[6]  += kvv * q1.z;  acc[7]  += kvv * q1.w;
        acc[8]  += kvv * q2.x;  acc[9]  += kvv * q2.y;
        acc[10] += kvv * q2.z;  acc[11] += kvv * q2.w;
        acc[12] += kvv * q3.x;  acc[13] += kvv * q3.y;
        acc[14] += kvv * q3.z;  acc[15] += kvv * q3.w;
      }
    }
    __syncthreads();
  }

  // two-stage red overlay: red2[s][r][h] at S[s*1088 + r*17 + h] (17-stride, 2-way max)
  if (w >= 4) {
    float* rp = S + (w - 4) * 1088 + lane * 17;
    #pragma unroll
    for (int h = 0; h < 16; h++) rp[h] = acc[h];
  }
  __syncthreads();
  if (w < 4) {
    float* rp = S + w * 1088 + lane * 17;
    #pragma unroll
    for (int h = 0; h < 16; h++) rp[h] += acc[h];
  }
  __syncthreads();

  // e-phase: wave w -> h = w and w+8, r = lane
  {
    float s1 = 0.f, s2 = 0.f;
    #pragma unroll
    for (int ss = 0; ss < 4; ss++) {
      s1 += S[ss * 1088 + lane * 17 + w];
      s2 += S[ss * 1088 + lane * 17 + w + 8];
    }
    s1 += qbk[b * NHD + w];
    s2 += qbk[b * NHD + w + 8];
    int mk = mask[b * TT + t0 + lane];
    float e1 = mk ? __expf(s1) : 0.f;
    float e2 = mk ? __expf(s2) : 0.f;
    S[E_OFF + lane * 20 + w] = e1;
    S[E_OFF + lane * 20 + w + 8] = e2;
    float sp1 = e1, sp2 = e2;
    #pragma unroll
    for (int m2 = 1; m2 < 64; m2 <<= 1) {
      sp1 += __shfl_xor(sp1, m2);
      sp2 += __shfl_xor(sp2, m2);
    }
    if (lane == 0) {
      Spart[(((size_t)b << 6) + g) * NHD + w] = sp1;
      Spart[(((size_t)b << 6) + g) * NHD + w + 8] = sp2;
    }
  }
  __syncthreads();

  // ---------------- PV pass ----------------
  STAGE(0, 0);
  __syncthreads();

  for (int c = 0; c < 16; c++) {
    if (c < 15) STAGE(c + 1, (c + 1) & 1);
    if (w < 4) {
      float4 p0 = make_float4(0.f, 0.f, 0.f, 0.f);
      float4 p1 = make_float4(0.f, 0.f, 0.f, 0.f);
      float4 p2 = make_float4(0.f, 0.f, 0.f, 0.f);
      float4 p3 = make_float4(0.f, 0.f, 0.f, 0.f);
      const float* sb = &S[(c & 1) << 12];
      #pragma unroll 8
      for (int rr = 0; rr < 16; rr++) {
        int row = (rsub << 4) + rr;
        float4 kvq = *(const float4*)&sb[(row << 6) + ((q15 ^ (row & 7)) << 2)];
        float4 ev  = *(const float4*)&S[E_OFF + row * 20 + (w << 2)];  // 2 addr/half -> free
        p0.x += kvq.x * ev.x; p0.y += kvq.y * ev.x; p0.z += kvq.z * ev.x; p0.w += kvq.w * ev.x;
        p1.x += kvq.x * ev.y; p1.y += kvq.y * ev.y; p1.z += kvq.z * ev.y; p1.w += kvq.w * ev.y;
        p2.x += kvq.x * ev.z; p2.y += kvq.y * ev.z; p2.z += kvq.z * ev.z; p2.w += kvq.w * ev.z;
        p3.x += kvq.x * ev.w; p3.y += kvq.y * ev.w; p3.z += kvq.z * ev.w; p3.w += kvq.w * ev.w;
      }
      // combine the 4 row-groups: lanes (l, l^16, l^32, l^48) share (iq, h)
      p0.x += __shfl_xor(p0.x, 16); p0.y += __shfl_xor(p0.y, 16);
      p0.z += __shfl_xor(p0.z, 16); p0.w += __shfl_xor(p0.w, 16);
      p1.x += __shfl_xor(p1.x, 16); p1.y += __shfl_xor(p1.y, 16);
      p1.z += __shfl_xor(p1.z, 16); p1.w += __shfl_xor(p1.w, 16);
      p2.x += __shfl_xor(p2.x, 16); p2.y += __shfl_xor(p2.y, 16);
      p2.z += __shfl_xor(p2.z, 16); p2.w += __shfl_xor(p2.w, 16);
      p3.x += __shfl_xor(p3.x, 16); p3.y += __shfl_xor(p3.y, 16);
      p3.z += __shfl_xor(p3.z, 16); p3.w += __shfl_xor(p3.w, 16);
      p0.x += __shfl_xor(p0.x, 32); p0.y += __shfl_xor(p0.y, 32);
      p0.z += __shfl_xor(p0.z, 32); p0.w += __shfl_xor(p0.w, 32);
      p1.x += __shfl_xor(p1.x, 32); p1.y += __shfl_xor(p1.y, 32);
      p1.z += __shfl_xor(p1.z, 32); p1.w += __shfl_xor(p1.w, 32);
      p2.x += __shfl_xor(p2.x, 32); p2.y += __shfl_xor(p2.y, 32);
      p2.z += __shfl_xor(p2.z, 32); p2.w += __shfl_xor(p2.w, 32);
      p3.x += __shfl_xor(p3.x, 32); p3.y += __shfl_xor(p3.y, 32);
      p3.z += __shfl_xor(p3.z, 32); p3.w += __shfl_xor(p3.w, 32);
      if (lane < 16) {
        float* cp = ctxp + ((((size_t)(b << 6) + g) * NHD + (w << 2)) << 10) +
                    (c << 6) + (lane << 2);
        *(float4*)(cp)        = p0;
        *(float4*)(cp + 1024) = p1;
        *(float4*)(cp + 2048) = p2;
        *(float4*)(cp + 3072) = p3;
      }
    }
    __syncthreads();
  }
  #undef STAGE
  #undef E_OFF
}

// ---------------- K4b: ctxin[b][h][i] = sum_g ctxp[b][g][h][i] ----------------
__global__ __launch_bounds__(256) void k_reduce(const float* __restrict__ ctxp,
                                                float* __restrict__ ctxin) {
  int tid = threadIdx.x;
  int b = blockIdx.x >> 4, h = blockIdx.x & 15;
  const float4* cp4 = (const float4*)ctxp;
  float4 s = make_float4(0.f, 0.f, 0.f, 0.f);
  #pragma unroll 8
  for (int g = 0; g < 64; g++) {
    float4 v = cp4[((((size_t)b * 64 + g) * 16 + h) << 8) + tid];
    s.x += v.x; s.y += v.y; s.z += v.z; s.w += v.w;
  }
  ((float4*)ctxin)[(((size_t)(b << 4) + h) << 8) + tid] = s;
}

// ---------------- K6: out (Sinv folded in from Spart) ----------------
__global__ __launch_bounds__(256) void k_out(const float* __restrict__ Wv,
                                             const float* __restrict__ bv,
                                             const float* __restrict__ ctxin,
                                             const float* __restrict__ Spart,
                                             float* __restrict__ out) {
  __shared__ float cs[BB * HH];  // 32 KB
  __shared__ float sp2[64];
  int tid = threadIdx.x;
  int h = blockIdx.x >> 4;
  int j0 = blockIdx.x * 4;
  #pragma unroll
  for (int m = 0; m < 8; m++) {
    int idx4 = tid + (m << 8);
    int b = idx4 >> 8, i4 = idx4 & 255;
    ((float4*)cs)[idx4] = ((const float4*)ctxin)[(((b << 4) + h) << 8) + i4];
  }
  if (tid < 64) {   // sp2[b*8+gg] = sum of 8 g's of Spart[b][*][h]
    int bb = tid >> 3, gg = tid & 7;
    float s = 0.f;
    #pragma unroll
    for (int k = 0; k < 8; k++)
      s += Spart[(size_t)((bb << 6) + (gg << 3) + k) * NHD + h];
    sp2[tid] = s;
  }
  __syncthreads();
  int jj = tid >> 6, lane = tid & 63;
  int j = j0 + jj;
  float acc[BB];
  #pragma unroll
  for (int b = 0; b < BB; b++) acc[b] = 0.f;
  #pragma unroll
  for (int k = 0; k < 4; k++) {
    int i = (k << 8) + (lane << 2);
    float4 w = *(const float4*)&Wv[(size_t)j * HH + i];
    #pragma unroll
    for (int b = 0; b < BB; b++) acc[b] += dot4(w, *(const float4*)&cs[b * HH + i]);
  }
  #pragma unroll
  for (int b = 0; b < BB; b++) {
    acc[b] += __shfl_xor(acc[b], 1);  acc[b] += __shfl_xor(acc[b], 2);
    acc[b] += __shfl_xor(acc[b], 4);  acc[b] += __shfl_xor(acc[b], 8);
    acc[b] += __shfl_xor(acc[b], 16); acc[b] += __shfl_xor(acc[b], 32);
  }
  if (lane == 0) {
    float bvj = bv[j];
    #pragma unroll
    for (int b = 0; b < BB; b++) {
      float sv = 0.f;
      #pragma unroll
      for (int k = 0; k < 8; k++) sv += sp2[(b << 3) + k];
      out[b * HH + j] = acc[b] / sv + bvj;
    }
  }
}

extern "C" void kernel_launch(void* const* d_in, const int* in_sizes, int n_in,
                              void* d_out, int out_size, void* d_ws, size_t ws_size,
                              hipStream_t stream) {
  const float* hid  = (const float*)d_in[0];  // (8, 4097, 1024)
  const float* cell = (const float*)d_in[1];  // (8, 1024)
  const float* Wq   = (const float*)d_in[2];
  const float* bq   = (const float*)d_in[3];
  const float* Wk   = (const float*)d_in[4];
  const float* bk   = (const float*)d_in[5];
  const float* Wv   = (const float*)d_in[6];
  const float* bv   = (const float*)d_in[7];
  const int*  mask  = (const int*)d_in[8];    // (8, 4096)
  float* out = (float*)d_out;                 // (8, 1024)

  float* ws = (float*)d_ws;
  float* qbuf    = ws;             // 8192
  float* qWkT    = ws + 8192;      // 131072   [b][i][16]
  float* qbk     = ws + 139264;    // 128
  float* Spart   = ws + 139392;    // 8192     [b][g(64)][16]
  float* ctxin   = ws + 147584;    // 131072   [b][h][1024]
  float* ctxp    = ws + 278656;    // 8388608  [b][g(64)][h][1024] partials

  hipLaunchKernelGGL(k_q,      dim3(256), dim3(256), 0, stream, cell, Wq, bq, qbuf);
  hipLaunchKernelGGL(k_qwk,    dim3(256), dim3(256), 0, stream, qbuf, Wk, bk, qWkT, qbk);
  hipLaunchKernelGGL(k_sctx,   dim3(512), dim3(512), 0, stream, hid, qWkT, qbk, mask, ctxp, Spart);
  hipLaunchKernelGGL(k_reduce, dim3(128), dim3(256), 0, stream, ctxp, ctxin);
  hipLaunchKernelGGL(k_out,    dim3(256), dim3(256), 0, stream, Wv, bv, ctxin, Spart, out);
}